// Round 6
// baseline (395.634 us; speedup 1.0000x reference)
//
#include <hip/hip_runtime.h>
#include <hip/hip_bf16.h>

#define T_LEN 1024
#define D_DIM 64
#define BATCH 32

// ---------------------------------------------------------------------------
// Kernel 1: pairwise Euclidean distance, GEMM-trick.
// 128x128 tile, 256 threads, 8x8 micro-tile. UNCHANGED (awaiting counters
// once dp drops below it; ~130us, tile-size-invariant so far).
// ---------------------------------------------------------------------------
#define BM 128
#define BN 128

__global__ __launch_bounds__(256, 2) void cost_kernel(const float* __restrict__ pred,
                                                      const float* __restrict__ targ,
                                                      float* __restrict__ cost) {
    const int b = blockIdx.z;
    const float* P = pred + (size_t)b * T_LEN * D_DIM;
    const float* Tg = targ + (size_t)b * T_LEN * D_DIM;
    float* C = cost + (size_t)b * T_LEN * T_LEN;
    const int row0 = blockIdx.y * BM;
    const int col0 = blockIdx.x * BN;

    __shared__ __align__(16) float ps[BM][D_DIM + 4];
    __shared__ __align__(16) float ts[D_DIM][BN + 4];
    __shared__ float p2[BM], t2[BN];

    const int tid = threadIdx.x;

#pragma unroll
    for (int it = 0; it < 8; ++it) {
        int f = tid + 256 * it;
        int row = f >> 4;
        int kc = f & 15;
        float4 v = *(const float4*)(P + (size_t)(row0 + row) * D_DIM + 4 * kc);
        *(float4*)&ps[row][4 * kc] = v;
    }
#pragma unroll
    for (int it = 0; it < 8; ++it) {
        int f = tid + 256 * it;
        int col = f >> 4;
        int kc = f & 15;
        float4 w = *(const float4*)(Tg + (size_t)(col0 + col) * D_DIM + 4 * kc);
        ts[4 * kc + 0][col] = w.x;
        ts[4 * kc + 1][col] = w.y;
        ts[4 * kc + 2][col] = w.z;
        ts[4 * kc + 3][col] = w.w;
    }
    __syncthreads();

    if (tid < 128) {
        float s = 0.0f;
        const float4* pr = (const float4*)&ps[tid][0];
#pragma unroll
        for (int q = 0; q < 16; ++q) {
            float4 v = pr[q];
            s += v.x * v.x; s += v.y * v.y; s += v.z * v.z; s += v.w * v.w;
        }
        p2[tid] = s;
    } else {
        int c = tid - 128;
        float s = 0.0f;
#pragma unroll
        for (int k = 0; k < 64; ++k) { float x = ts[k][c]; s += x * x; }
        t2[c] = s;
    }
    __syncthreads();

    const int tx = tid & 15;
    const int ty = tid >> 4;
    const int cl = 4 * tx;
    const int ch = 64 + 4 * tx;

    float acc[8][8];
#pragma unroll
    for (int i = 0; i < 8; ++i)
#pragma unroll
        for (int j = 0; j < 8; ++j) acc[i][j] = 0.0f;

#pragma unroll
    for (int k4 = 0; k4 < 16; ++k4) {
        float4 bl[4], bh[4];
#pragma unroll
        for (int kk = 0; kk < 4; ++kk) {
            bl[kk] = *(const float4*)&ts[4 * k4 + kk][cl];
            bh[kk] = *(const float4*)&ts[4 * k4 + kk][ch];
        }
#pragma unroll
        for (int ih = 0; ih < 2; ++ih) {
#pragma unroll
            for (int i = 0; i < 4; ++i) {
                const int rr = (ih ? 64 + 4 * ty : 4 * ty) + i;
                float4 av = *(const float4*)&ps[rr][4 * k4];
                const float a4[4] = {av.x, av.y, av.z, av.w};
                float* A = acc[4 * ih + i];
#pragma unroll
                for (int kk = 0; kk < 4; ++kk) {
                    const float* blp = (const float*)&bl[kk];
                    const float* bhp = (const float*)&bh[kk];
                    const float ak = a4[kk];
#pragma unroll
                    for (int j = 0; j < 4; ++j) {
                        A[j]     += ak * blp[j];
                        A[4 + j] += ak * bhp[j];
                    }
                }
            }
        }
    }

    float4 tlo = *(const float4*)&t2[cl];
    float4 thi = *(const float4*)&t2[ch];
    const float* tl = (const float*)&tlo;
    const float* th = (const float*)&thi;
#pragma unroll
    for (int ih = 0; ih < 2; ++ih) {
#pragma unroll
        for (int i = 0; i < 4; ++i) {
            const int rr = (ih ? 64 + 4 * ty : 4 * ty) + i;
            const float pa = p2[rr];
            float* A = acc[4 * ih + i];
            float4 o1, o2;
            o1.x = sqrtf(fmaxf(pa + tl[0] - 2.0f * A[0], 1e-12f));
            o1.y = sqrtf(fmaxf(pa + tl[1] - 2.0f * A[1], 1e-12f));
            o1.z = sqrtf(fmaxf(pa + tl[2] - 2.0f * A[2], 1e-12f));
            o1.w = sqrtf(fmaxf(pa + tl[3] - 2.0f * A[3], 1e-12f));
            o2.x = sqrtf(fmaxf(pa + th[0] - 2.0f * A[4], 1e-12f));
            o2.y = sqrtf(fmaxf(pa + th[1] - 2.0f * A[5], 1e-12f));
            o2.z = sqrtf(fmaxf(pa + th[2] - 2.0f * A[6], 1e-12f));
            o2.w = sqrtf(fmaxf(pa + th[3] - 2.0f * A[7], 1e-12f));
            float* Crow = C + (size_t)(row0 + rr) * T_LEN + col0;
            *(float4*)(Crow + cl) = o1;
            *(float4*)(Crow + ch) = o2;
        }
    }
}

// ---------------------------------------------------------------------------
// Kernel 2: Frechet DP, one wave per batch, time-skewed, ONE row per step.
// The mechanism that killed rounds 0-5: LLVM's machine scheduler sinks loads
// to their uses (live-range shortening), collapsing every source-level
// pipeline. Fix: PLAIN float4 loads (so SIInsertWaitcnts emits precise
// counted vmcnt(28) per-register) + sched_barrier(0) fences between each
// step's refill-issue and its compute. Loads for step s+8 are separated
// from their use by 16 fences the scheduler cannot cross -> values stay
// live in VGPRs (launch_bounds(64,1): 512 VGPR budget; expect ~200 used).
// Rotation via fresh temps n0..n3 copied into slot names after consume
// (copy-prop coalesces, no moves).
// Recurrence: max(c,min(min(up,left),diag)) == med3(left,c,max(c,min(up,diag)))
// — validated absmax=0 in rounds 3/4/5.
// ---------------------------------------------------------------------------
#define PD 8

__global__ __launch_bounds__(64, 1) void dp_kernel(const float* __restrict__ cost,
                                                   float* __restrict__ out) {
    const int b = blockIdx.x;
    const int t = threadIdx.x;  // lane 0..63
    const float INF = __builtin_inff();
    const float* C = cost + (size_t)b * T_LEN * T_LEN + 16 * t;

    float prev[16];
#pragma unroll
    for (int j = 0; j < 16; ++j) prev[j] = INF;
    float right_out = INF;
    float diag_feed = INF;

    // 8 slots x 4 float4, individually named.
    float4 A0, A1, A2, A3, B0, B1, B2, B3, C0_, C1_, C2_, C3_, D0_, D1_, D2_, D3_;
    float4 E0, E1, E2, E3, F0, F1, F2, F3, G0, G1, G2, G3, H0, H1, H2, H3;

#define DP_FILL(D, P0, P1, P2, P3)                                            \
    {                                                                         \
        int r = (D) - t; r = r < 0 ? 0 : r;                                   \
        const float4* p = (const float4*)(C + (size_t)r * T_LEN);             \
        P0 = p[0]; P1 = p[1]; P2 = p[2]; P3 = p[3];                           \
    }
    DP_FILL(0, A0, A1, A2, A3)
    DP_FILL(1, B0, B1, B2, B3)
    DP_FILL(2, C0_, C1_, C2_, C3_)
    DP_FILL(3, D0_, D1_, D2_, D3_)
    DP_FILL(4, E0, E1, E2, E3)
    DP_FILL(5, F0, F1, F2, F3)
    DP_FILL(6, G0, G1, G2, G3)
    DP_FILL(7, H0, H1, H2, H3)
#undef DP_FILL
    __builtin_amdgcn_sched_barrier(0);

    const int S = T_LEN + 63;                 // 1087 real steps
    const int NCH = (S + PD - 1) / PD;        // 136 chunks -> 1088 steps (tail guarded)
    int s = 0;

#define DP_STEP(P0, P1, P2, P3)                                               \
    {                                                                         \
        /* issue refill loads for step s+PD (plain loads; fenced below) */    \
        float4 n0, n1, n2, n3;                                                \
        {                                                                     \
            int rn = s + PD - t;                                              \
            rn = rn < 0 ? 0 : (rn > T_LEN - 1 ? T_LEN - 1 : rn);              \
            const float4* p = (const float4*)(C + (size_t)rn * T_LEN);        \
            n0 = p[0]; n1 = p[1]; n2 = p[2]; n3 = p[3];                       \
        }                                                                     \
        __builtin_amdgcn_sched_barrier(0);                                    \
        /* consume slot loaded PD steps (>=16 fences) ago */                  \
        const int r = s - t;                                                  \
        float inc = __shfl_up(right_out, 1, 64);                              \
        float left = inc, diag = diag_feed;                                   \
        diag_feed = inc;                                                      \
        if (t == 0) { left = (r == 0) ? -INF : INF; diag = INF; }             \
        if (r >= 0 && r < T_LEN) {                                            \
            float cq[16] = {P0.x, P0.y, P0.z, P0.w, P1.x, P1.y, P1.z, P1.w,   \
                            P2.x, P2.y, P2.z, P2.w, P3.x, P3.y, P3.z, P3.w};  \
            float g[16];                                                      \
            g[0] = fmaxf(cq[0], fminf(prev[0], diag));                        \
            _Pragma("unroll")                                                 \
            for (int j = 1; j < 16; ++j)                                      \
                g[j] = fmaxf(cq[j], fminf(prev[j], prev[j - 1]));             \
            float v = left;                                                   \
            _Pragma("unroll")                                                 \
            for (int j = 0; j < 16; ++j) {                                    \
                v = __builtin_amdgcn_fmed3f(v, cq[j], g[j]);                  \
                prev[j] = v;                                                  \
            }                                                                 \
            right_out = v;                                                    \
        }                                                                     \
        /* rotate slot to the newly loaded values (copy-prop, no moves) */    \
        P0 = n0; P1 = n1; P2 = n2; P3 = n3;                                   \
        __builtin_amdgcn_sched_barrier(0);                                    \
        ++s;                                                                  \
    }

    for (int chunk = 0; chunk < NCH; ++chunk) {
        DP_STEP(A0, A1, A2, A3)
        DP_STEP(B0, B1, B2, B3)
        DP_STEP(C0_, C1_, C2_, C3_)
        DP_STEP(D0_, D1_, D2_, D3_)
        DP_STEP(E0, E1, E2, E3)
        DP_STEP(F0, F1, F2, F3)
        DP_STEP(G0, G1, G2, G3)
        DP_STEP(H0, H1, H2, H3)
    }
#undef DP_STEP

    if (t == 63) atomicAdd(out, prev[15] * (1.0f / (float)BATCH));
}

// ---------------------------------------------------------------------------
// Fallback: fused DP computing distances on the fly (only if ws can't hold
// one 4 MB cost matrix). Unchanged.
// ---------------------------------------------------------------------------
__global__ __launch_bounds__(64) void dp_fused_kernel(const float* __restrict__ pred,
                                                      const float* __restrict__ targ,
                                                      float* __restrict__ out) {
    const int b = blockIdx.x;
    const int t = threadIdx.x;
    const float INF = __builtin_inff();
    const float* P = pred + (size_t)b * T_LEN * D_DIM;
    const float* T = targ + (size_t)b * T_LEN * D_DIM + (size_t)(16 * t) * D_DIM;

    float prev[16];
#pragma unroll
    for (int j = 0; j < 16; ++j) prev[j] = INF;
    float right_out = INF;
    float diag_feed = INF;

    for (int s = 0; s < T_LEN + 63; s++) {
        int r = s - t;
        float inc = __shfl_up(right_out, 1, 64);
        float left = inc, diag = diag_feed;
        diag_feed = inc;
        if (t == 0) { left = (r == 0) ? -INF : INF; diag = INF; }
        if (r >= 0 && r < T_LEN) {
            float4 pr[16];
            const float4* pp = (const float4*)(P + (size_t)r * D_DIM);
#pragma unroll
            for (int q = 0; q < 16; q++) pr[q] = pp[q];
#pragma unroll
            for (int j = 0; j < 16; j++) {
                const float4* tp = (const float4*)(T + (size_t)j * D_DIM);
                float acc = 0.0f;
#pragma unroll
                for (int q = 0; q < 16; q++) {
                    float4 tv = tp[q];
                    float dx = pr[q].x - tv.x; acc += dx * dx;
                    float dy = pr[q].y - tv.y; acc += dy * dy;
                    float dz = pr[q].z - tv.z; acc += dz * dz;
                    float dw = pr[q].w - tv.w; acc += dw * dw;
                }
                float c = sqrtf(fmaxf(acc, 1e-12f));
                float up = prev[j];
                float v = fmaxf(c, fminf(fminf(up, diag), left));
                diag = up; left = v; prev[j] = v;
            }
            right_out = left;
        }
    }
    if (t == 63) atomicAdd(out, prev[15] * (1.0f / (float)BATCH));
}

extern "C" void kernel_launch(void* const* d_in, const int* in_sizes, int n_in,
                              void* d_out, int out_size, void* d_ws, size_t ws_size,
                              hipStream_t stream) {
    const float* pred = (const float*)d_in[0];
    const float* targ = (const float*)d_in[1];
    float* out = (float*)d_out;

    hipMemsetAsync(out, 0, sizeof(float) * out_size, stream);

    const size_t per_batch = (size_t)T_LEN * T_LEN * sizeof(float);  // 4 MB
    int bpg = (int)(ws_size / per_batch);
    if (bpg > BATCH) bpg = BATCH;

    if (bpg >= 1) {
        float* cost = (float*)d_ws;
        for (int g0 = 0; g0 < BATCH; g0 += bpg) {
            int gb = (BATCH - g0) < bpg ? (BATCH - g0) : bpg;
            dim3 grid(T_LEN / BN, T_LEN / BM, gb);
            cost_kernel<<<grid, 256, 0, stream>>>(pred + (size_t)g0 * T_LEN * D_DIM,
                                                  targ + (size_t)g0 * T_LEN * D_DIM,
                                                  cost);
            dp_kernel<<<gb, 64, 0, stream>>>(cost, out);
        }
    } else {
        dp_fused_kernel<<<BATCH, 64, 0, stream>>>(pred, targ, out);
    }
}

// Round 7
// 391.894 us; speedup vs baseline: 1.0095x; 1.0095x over previous
//
#include <hip/hip_runtime.h>
#include <hip/hip_bf16.h>

#define T_LEN 1024
#define D_DIM 64
#define BATCH 32

// ---------------------------------------------------------------------------
// Kernel 1: pairwise Euclidean distance, GEMM-trick.
// 128x128 tile, 256 threads, 8x8 micro-tile. UNCHANGED (counters surface
// once dp drops below it).
// ---------------------------------------------------------------------------
#define BM 128
#define BN 128

__global__ __launch_bounds__(256, 2) void cost_kernel(const float* __restrict__ pred,
                                                      const float* __restrict__ targ,
                                                      float* __restrict__ cost) {
    const int b = blockIdx.z;
    const float* P = pred + (size_t)b * T_LEN * D_DIM;
    const float* Tg = targ + (size_t)b * T_LEN * D_DIM;
    float* C = cost + (size_t)b * T_LEN * T_LEN;
    const int row0 = blockIdx.y * BM;
    const int col0 = blockIdx.x * BN;

    __shared__ __align__(16) float ps[BM][D_DIM + 4];
    __shared__ __align__(16) float ts[D_DIM][BN + 4];
    __shared__ float p2[BM], t2[BN];

    const int tid = threadIdx.x;

#pragma unroll
    for (int it = 0; it < 8; ++it) {
        int f = tid + 256 * it;
        int row = f >> 4;
        int kc = f & 15;
        float4 v = *(const float4*)(P + (size_t)(row0 + row) * D_DIM + 4 * kc);
        *(float4*)&ps[row][4 * kc] = v;
    }
#pragma unroll
    for (int it = 0; it < 8; ++it) {
        int f = tid + 256 * it;
        int col = f >> 4;
        int kc = f & 15;
        float4 w = *(const float4*)(Tg + (size_t)(col0 + col) * D_DIM + 4 * kc);
        ts[4 * kc + 0][col] = w.x;
        ts[4 * kc + 1][col] = w.y;
        ts[4 * kc + 2][col] = w.z;
        ts[4 * kc + 3][col] = w.w;
    }
    __syncthreads();

    if (tid < 128) {
        float s = 0.0f;
        const float4* pr = (const float4*)&ps[tid][0];
#pragma unroll
        for (int q = 0; q < 16; ++q) {
            float4 v = pr[q];
            s += v.x * v.x; s += v.y * v.y; s += v.z * v.z; s += v.w * v.w;
        }
        p2[tid] = s;
    } else {
        int c = tid - 128;
        float s = 0.0f;
#pragma unroll
        for (int k = 0; k < 64; ++k) { float x = ts[k][c]; s += x * x; }
        t2[c] = s;
    }
    __syncthreads();

    const int tx = tid & 15;
    const int ty = tid >> 4;
    const int cl = 4 * tx;
    const int ch = 64 + 4 * tx;

    float acc[8][8];
#pragma unroll
    for (int i = 0; i < 8; ++i)
#pragma unroll
        for (int j = 0; j < 8; ++j) acc[i][j] = 0.0f;

#pragma unroll
    for (int k4 = 0; k4 < 16; ++k4) {
        float4 bl[4], bh[4];
#pragma unroll
        for (int kk = 0; kk < 4; ++kk) {
            bl[kk] = *(const float4*)&ts[4 * k4 + kk][cl];
            bh[kk] = *(const float4*)&ts[4 * k4 + kk][ch];
        }
#pragma unroll
        for (int ih = 0; ih < 2; ++ih) {
#pragma unroll
            for (int i = 0; i < 4; ++i) {
                const int rr = (ih ? 64 + 4 * ty : 4 * ty) + i;
                float4 av = *(const float4*)&ps[rr][4 * k4];
                const float a4[4] = {av.x, av.y, av.z, av.w};
                float* A = acc[4 * ih + i];
#pragma unroll
                for (int kk = 0; kk < 4; ++kk) {
                    const float* blp = (const float*)&bl[kk];
                    const float* bhp = (const float*)&bh[kk];
                    const float ak = a4[kk];
#pragma unroll
                    for (int j = 0; j < 4; ++j) {
                        A[j]     += ak * blp[j];
                        A[4 + j] += ak * bhp[j];
                    }
                }
            }
        }
    }

    float4 tlo = *(const float4*)&t2[cl];
    float4 thi = *(const float4*)&t2[ch];
    const float* tl = (const float*)&tlo;
    const float* th = (const float*)&thi;
#pragma unroll
    for (int ih = 0; ih < 2; ++ih) {
#pragma unroll
        for (int i = 0; i < 4; ++i) {
            const int rr = (ih ? 64 + 4 * ty : 4 * ty) + i;
            const float pa = p2[rr];
            float* A = acc[4 * ih + i];
            float4 o1, o2;
            o1.x = sqrtf(fmaxf(pa + tl[0] - 2.0f * A[0], 1e-12f));
            o1.y = sqrtf(fmaxf(pa + tl[1] - 2.0f * A[1], 1e-12f));
            o1.z = sqrtf(fmaxf(pa + tl[2] - 2.0f * A[2], 1e-12f));
            o1.w = sqrtf(fmaxf(pa + tl[3] - 2.0f * A[3], 1e-12f));
            o2.x = sqrtf(fmaxf(pa + th[0] - 2.0f * A[4], 1e-12f));
            o2.y = sqrtf(fmaxf(pa + th[1] - 2.0f * A[5], 1e-12f));
            o2.z = sqrtf(fmaxf(pa + th[2] - 2.0f * A[6], 1e-12f));
            o2.w = sqrtf(fmaxf(pa + th[3] - 2.0f * A[7], 1e-12f));
            float* Crow = C + (size_t)(row0 + rr) * T_LEN + col0;
            *(float4*)(Crow + cl) = o1;
            *(float4*)(Crow + ch) = o2;
        }
    }
}

// ---------------------------------------------------------------------------
// Kernel 2: Frechet DP — PRODUCER/CONSUMER WAVE PAIR per batch.
// Rounds 0-6 lesson: with one wave/CU, every residual wait exposes a full
// memory latency per step; no source-level schedule survives the toolchain.
// Structural fix: wave 1 (producer) issues global_load_lds (per-lane skewed
// row-slice gather, diagonal of the cost matrix) into a 12-step LDS ring,
// flagged in 4-step groups, running up to ~8 steps (~1400cy) ahead. Wave 0
// (consumer) does NO vmem: 4 conflict-free ds_read_b128 + med3 chain per
// step. All conservative compiler drains land on the producer (slack);
// consumer waits only on precise lgkmcnt + one flag spin per 4 steps.
// Sync: volatile LDS flags + workgroup acquire/release fences.
// Recurrence: max(c,min(min(up,left),diag)) == med3(left,c,max(c,min(up,diag)))
// — validated absmax=0 in rounds 3-6.
// ---------------------------------------------------------------------------
#define RING 12   // LDS step-slots (12 x 4KB = 48KB)
#define GRP 4     // steps per flag group (RING/GRP = 3 group-slots)
#define NGRP 272  // ceil(1087/4) -> 1088 steps, tail guarded

#define GLDS(SRC, LDSP, OFF)                                                  \
    __builtin_amdgcn_global_load_lds(                                         \
        (const __attribute__((address_space(1))) unsigned int*)(const void*)(SRC), \
        (__attribute__((address_space(3))) unsigned int*)(LDSP), 16, (OFF), 0)

__global__ __launch_bounds__(128, 1) void dp_kernel(const float* __restrict__ cost,
                                                    float* __restrict__ out) {
    const int b = blockIdx.x;
    const int tid = threadIdx.x;
    const float INF = __builtin_inff();
    const float* Cb = cost + (size_t)b * T_LEN * T_LEN;

    // ring4[slot][q][lane]: step s slice for lane l lives at [s%RING][q][l],
    // holding C[s-l][16l+4q .. +4). Consumer b128 reads are stride-16B across
    // lanes (the proven conflict-free pattern); producer writes are the
    // hardware-linear lane*16 of global_load_lds.
    __shared__ __align__(16) float4 ring4[RING][4][64];
    __shared__ int ready[3];
    __shared__ int done[3];
    volatile int* vready = ready;
    volatile int* vdone = done;

    if (tid == 0) {
#pragma unroll
        for (int i = 0; i < 3; ++i) { ready[i] = -1; done[i] = i - 3; }
    }
    __syncthreads();

    if (tid >= 64) {
        // ---------------- producer wave ----------------
        const int l = tid - 64;

#define PROD_ISSUE(G)                                                         \
        {                                                                     \
            const int gs = (G) % 3;                                           \
            _Pragma("unroll")                                                 \
            for (int u = 0; u < GRP; ++u) {                                   \
                int s = GRP * (G) + u;                                        \
                int r = s - l;                                                \
                r = r < 0 ? 0 : (r > T_LEN - 1 ? T_LEN - 1 : r);              \
                const float* src = Cb + (size_t)r * T_LEN + 16 * l;           \
                GLDS(src, &ring4[gs * GRP + u][0][0], 0);                     \
                GLDS(src, &ring4[gs * GRP + u][1][0], 16);                    \
                GLDS(src, &ring4[gs * GRP + u][2][0], 32);                    \
                GLDS(src, &ring4[gs * GRP + u][3][0], 48);                    \
            }                                                                 \
        }

        // group 0: slot trivially free
        PROD_ISSUE(0)
        for (int g = 0; g < NGRP; ++g) {
            if (g + 1 < NGRP) {
                const int ns = (g + 1) % 3;
                while (vdone[ns] != (g + 1) - 3) __builtin_amdgcn_s_sleep(2);
                __builtin_amdgcn_fence(__ATOMIC_ACQUIRE, "workgroup");
                PROD_ISSUE(g + 1)
                // group g's 16 loads are the oldest; <=16 outstanding left
                // means they are complete. (Compiler may strengthen to
                // vmcnt(0) before the flag write; correctness unaffected.)
                asm volatile("s_waitcnt vmcnt(16)" ::: "memory");
            } else {
                asm volatile("s_waitcnt vmcnt(0)" ::: "memory");
            }
            __builtin_amdgcn_fence(__ATOMIC_RELEASE, "workgroup");
            vready[g % 3] = g;
        }
#undef PROD_ISSUE
    } else {
        // ---------------- consumer wave ----------------
        const int t = tid;
        float prev[16];
#pragma unroll
        for (int j = 0; j < 16; ++j) prev[j] = INF;
        float right_out = INF;
        float diag_feed = INF;

        int gslot = 0;
        for (int g = 0; g < NGRP; ++g) {
            while (vready[gslot] != g) __builtin_amdgcn_s_sleep(2);
            __builtin_amdgcn_fence(__ATOMIC_ACQUIRE, "workgroup");
#pragma unroll
            for (int u = 0; u < GRP; ++u) {
                const int s = GRP * g + u;
                const int r = s - t;
                float4 q0 = ring4[gslot * GRP + u][0][t];
                float4 q1 = ring4[gslot * GRP + u][1][t];
                float4 q2 = ring4[gslot * GRP + u][2][t];
                float4 q3 = ring4[gslot * GRP + u][3][t];
                float inc = __shfl_up(right_out, 1, 64);
                float left = inc, diag = diag_feed;
                diag_feed = inc;
                if (t == 0) { left = (r == 0) ? -INF : INF; diag = INF; }
                if (r >= 0 && r < T_LEN) {
                    float cq[16] = {q0.x, q0.y, q0.z, q0.w, q1.x, q1.y, q1.z, q1.w,
                                    q2.x, q2.y, q2.z, q2.w, q3.x, q3.y, q3.z, q3.w};
                    float gg[16];
                    gg[0] = fmaxf(cq[0], fminf(prev[0], diag));
#pragma unroll
                    for (int j = 1; j < 16; ++j)
                        gg[j] = fmaxf(cq[j], fminf(prev[j], prev[j - 1]));
                    float v = left;
#pragma unroll
                    for (int j = 0; j < 16; ++j) {
                        v = __builtin_amdgcn_fmed3f(v, cq[j], gg[j]);
                        prev[j] = v;
                    }
                    right_out = v;
                }
            }
            __builtin_amdgcn_fence(__ATOMIC_RELEASE, "workgroup");
            vdone[gslot] = g;
            gslot = (gslot == 2) ? 0 : gslot + 1;
        }
        if (t == 63) atomicAdd(out, prev[15] * (1.0f / (float)BATCH));
    }
}

// ---------------------------------------------------------------------------
// Fallback: fused DP computing distances on the fly (only if ws can't hold
// one 4 MB cost matrix). Unchanged.
// ---------------------------------------------------------------------------
__global__ __launch_bounds__(64) void dp_fused_kernel(const float* __restrict__ pred,
                                                      const float* __restrict__ targ,
                                                      float* __restrict__ out) {
    const int b = blockIdx.x;
    const int t = threadIdx.x;
    const float INF = __builtin_inff();
    const float* P = pred + (size_t)b * T_LEN * D_DIM;
    const float* T = targ + (size_t)b * T_LEN * D_DIM + (size_t)(16 * t) * D_DIM;

    float prev[16];
#pragma unroll
    for (int j = 0; j < 16; ++j) prev[j] = INF;
    float right_out = INF;
    float diag_feed = INF;

    for (int s = 0; s < T_LEN + 63; s++) {
        int r = s - t;
        float inc = __shfl_up(right_out, 1, 64);
        float left = inc, diag = diag_feed;
        diag_feed = inc;
        if (t == 0) { left = (r == 0) ? -INF : INF; diag = INF; }
        if (r >= 0 && r < T_LEN) {
            float4 pr[16];
            const float4* pp = (const float4*)(P + (size_t)r * D_DIM);
#pragma unroll
            for (int q = 0; q < 16; q++) pr[q] = pp[q];
#pragma unroll
            for (int j = 0; j < 16; j++) {
                const float4* tp = (const float4*)(T + (size_t)j * D_DIM);
                float acc = 0.0f;
#pragma unroll
                for (int q = 0; q < 16; q++) {
                    float4 tv = tp[q];
                    float dx = pr[q].x - tv.x; acc += dx * dx;
                    float dy = pr[q].y - tv.y; acc += dy * dy;
                    float dz = pr[q].z - tv.z; acc += dz * dz;
                    float dw = pr[q].w - tv.w; acc += dw * dw;
                }
                float c = sqrtf(fmaxf(acc, 1e-12f));
                float up = prev[j];
                float v = fmaxf(c, fminf(fminf(up, diag), left));
                diag = up; left = v; prev[j] = v;
            }
            right_out = left;
        }
    }
    if (t == 63) atomicAdd(out, prev[15] * (1.0f / (float)BATCH));
}

extern "C" void kernel_launch(void* const* d_in, const int* in_sizes, int n_in,
                              void* d_out, int out_size, void* d_ws, size_t ws_size,
                              hipStream_t stream) {
    const float* pred = (const float*)d_in[0];
    const float* targ = (const float*)d_in[1];
    float* out = (float*)d_out;

    hipMemsetAsync(out, 0, sizeof(float) * out_size, stream);

    const size_t per_batch = (size_t)T_LEN * T_LEN * sizeof(float);  // 4 MB
    int bpg = (int)(ws_size / per_batch);
    if (bpg > BATCH) bpg = BATCH;

    if (bpg >= 1) {
        float* cost = (float*)d_ws;
        for (int g0 = 0; g0 < BATCH; g0 += bpg) {
            int gb = (BATCH - g0) < bpg ? (BATCH - g0) : bpg;
            dim3 grid(T_LEN / BN, T_LEN / BM, gb);
            cost_kernel<<<grid, 256, 0, stream>>>(pred + (size_t)g0 * T_LEN * D_DIM,
                                                  targ + (size_t)g0 * T_LEN * D_DIM,
                                                  cost);
            dp_kernel<<<gb, 128, 0, stream>>>(cost, out);
        }
    } else {
        dp_fused_kernel<<<BATCH, 64, 0, stream>>>(pred, targ, out);
    }
}